// Round 1
// baseline (118.512 us; speedup 1.0000x reference)
//
#include <hip/hip_runtime.h>
#include <hip/hip_bf16.h>

// Problem: B=8, S=2048, D_MODEL=1024, D_K=D_V=64, causal attention, fp32 in/out.
// ws layout: Qb bf16[16384][64] | Kb bf16[16384][64] | Vt bf16[8][64][2048]  (6 MB)

typedef __attribute__((ext_vector_type(4))) float f32x4;
typedef __attribute__((ext_vector_type(8))) short short8;
typedef __attribute__((ext_vector_type(4))) short short4v;

#define MFMA16(a, b, c) __builtin_amdgcn_mfma_f32_16x16x32_bf16((a), (b), (c), 0, 0, 0)

__device__ __forceinline__ unsigned short f2bf(float f) {
    // round-to-nearest-even fp32 -> bf16
    unsigned int u = __float_as_uint(f);
    unsigned int r = (u + 0x7FFFu + ((u >> 16) & 1u)) >> 16;
    return (unsigned short)r;
}

__device__ __forceinline__ f32x4 zero4() {
    f32x4 z = {0.f, 0.f, 0.f, 0.f};
    return z;
}

// ---------------------------------------------------------------------------
// Kernel 1: QKV projection. C[m][n] = sum_k x[m][k] * W[n][k]  (gemm_bt form)
// BM=64, BN=192 (Q|K|V), BK=64, 4 waves each: 64 rows x 48 cols -> acc[4][3].
// ---------------------------------------------------------------------------
__global__ __launch_bounds__(256) void qkv_proj(
    const float* __restrict__ x,
    const float* __restrict__ wq,
    const float* __restrict__ wk,
    const float* __restrict__ wv,
    unsigned short* __restrict__ Qb,
    unsigned short* __restrict__ Kb,
    unsigned short* __restrict__ Vt)
{
    // padded stride 72 bf16 = 144 B: 16B-aligned (b128 ok), rows spread over banks
    __shared__ __align__(16) unsigned short Alds[64][72];
    __shared__ __align__(16) unsigned short Blds[192][72];

    const int tid  = threadIdx.x;
    const int lane = tid & 63;
    const int wid  = tid >> 6;       // wave 0..3
    const int c16  = lane & 15;
    const int g    = lane >> 4;
    const long m0  = (long)blockIdx.x * 64;

    f32x4 acc[4][3];
    #pragma unroll
    for (int i = 0; i < 4; ++i)
        #pragma unroll
        for (int j = 0; j < 3; ++j)
            acc[i][j] = zero4();

    for (int k0 = 0; k0 < 1024; k0 += 64) {
        __syncthreads();   // WAR: previous chunk's LDS reads done
        // stage A: 64 rows x 64 fp32 -> bf16   (1024 float4, 4 per thread)
        #pragma unroll
        for (int i = 0; i < 4; ++i) {
            int idx = tid + i * 256;
            int r = idx >> 4, c4 = idx & 15;
            f32x4 v = *(const f32x4*)(x + (m0 + r) * 1024 + k0 + c4 * 4);
            short4v p = { (short)f2bf(v[0]), (short)f2bf(v[1]),
                          (short)f2bf(v[2]), (short)f2bf(v[3]) };
            *(short4v*)&Alds[r][c4 * 4] = p;
        }
        // stage B: 192 weight rows x 64 fp32 -> bf16  (3072 float4, 12 per thread)
        #pragma unroll
        for (int i = 0; i < 12; ++i) {
            int idx = tid + i * 256;
            int r = idx >> 4, c4 = idx & 15;
            const float* wsrc = (r < 64)  ? (wq + (long)r * 1024)
                              : (r < 128) ? (wk + (long)(r - 64) * 1024)
                              :             (wv + (long)(r - 128) * 1024);
            f32x4 v = *(const f32x4*)(wsrc + k0 + c4 * 4);
            short4v p = { (short)f2bf(v[0]), (short)f2bf(v[1]),
                          (short)f2bf(v[2]), (short)f2bf(v[3]) };
            *(short4v*)&Blds[r][c4 * 4] = p;
        }
        __syncthreads();
        #pragma unroll
        for (int kc = 0; kc < 2; ++kc) {
            short8 af[4], bfv[3];
            #pragma unroll
            for (int mt = 0; mt < 4; ++mt)
                af[mt] = *(const short8*)&Alds[mt * 16 + c16][kc * 32 + g * 8];
            #pragma unroll
            for (int nt = 0; nt < 3; ++nt)
                bfv[nt] = *(const short8*)&Blds[wid * 48 + nt * 16 + c16][kc * 32 + g * 8];
            #pragma unroll
            for (int mt = 0; mt < 4; ++mt)
                #pragma unroll
                for (int nt = 0; nt < 3; ++nt)
                    acc[mt][nt] = MFMA16(af[mt], bfv[nt], acc[mt][nt]);
        }
    }

    // epilogue: C/D layout col=lane&15, row=(lane>>4)*4+r
    #pragma unroll
    for (int mt = 0; mt < 4; ++mt) {
        #pragma unroll
        for (int nt = 0; nt < 3; ++nt) {
            int n = wid * 48 + nt * 16 + c16;
            #pragma unroll
            for (int r = 0; r < 4; ++r) {
                long m = m0 + mt * 16 + g * 4 + r;
                unsigned short hv = f2bf(acc[mt][nt][r]);
                if (n < 64) {
                    Qb[m * 64 + n] = hv;
                } else if (n < 128) {
                    Kb[m * 64 + (n - 64)] = hv;
                } else {
                    long bb = m >> 11;        // batch
                    long ss = m & 2047;       // seq pos
                    Vt[(bb * 64 + (n - 128)) * 2048 + ss] = hv;   // V transposed
                }
            }
        }
    }
}

// ---------------------------------------------------------------------------
// Kernel 2: causal flash attention. One wave (64 thr) per 16-row Q tile.
// KV step = 32. S = mfma(Q, K) (gemm_bt), PV = mfma(P, Vt) (gemm_bt, V^T).
// Blocks launched in descending kv-length order for load balance.
// ---------------------------------------------------------------------------
__global__ __launch_bounds__(64) void attn_fwd(
    const unsigned short* __restrict__ Qb,
    const unsigned short* __restrict__ Kb,
    const unsigned short* __restrict__ Vt,
    float* __restrict__ out)
{
    __shared__ __align__(16) unsigned short Plds[16][72];

    const int lane = threadIdx.x;
    const int c16  = lane & 15;
    const int g    = lane >> 4;
    const int t    = blockIdx.x;
    const int b    = t & 7;
    const int qt   = 127 - (t >> 3);   // descending: longest tiles first
    const int q0   = qt * 16;

    // Q fragments (held in regs for the whole kv loop)
    const unsigned short* qrow = Qb + ((long)b * 2048 + q0 + c16) * 64;
    const short8 qf0 = *(const short8*)(qrow + g * 8);
    const short8 qf1 = *(const short8*)(qrow + 32 + g * 8);

    const unsigned short* Kbase = Kb + (long)b * 2048 * 64;
    const unsigned short* Vbase = Vt + (long)b * 64 * 2048;

    f32x4 acc[4];
    #pragma unroll
    for (int vt = 0; vt < 4; ++vt) acc[vt] = zero4();
    float m_r[4], l_r[4];
    #pragma unroll
    for (int r = 0; r < 4; ++r) { m_r[r] = -1e30f; l_r[r] = 0.f; }

    const float LOG2E = 1.44269504088896f;
    const int n_kv = q0 + 16;

    for (int kv0 = 0; kv0 < n_kv; kv0 += 32) {
        // ---- S = Q K^T for 16 x 32 tile (2 col-tiles x 2 k-chunks) ----
        f32x4 s[2];
        #pragma unroll
        for (int nt = 0; nt < 2; ++nt) {
            const unsigned short* krow = Kbase + (long)(kv0 + nt * 16 + c16) * 64;
            short8 kf0 = *(const short8*)(krow + g * 8);
            short8 kf1 = *(const short8*)(krow + 32 + g * 8);
            f32x4 z = zero4();
            z = MFMA16(qf0, kf0, z);
            z = MFMA16(qf1, kf1, z);
            s[nt] = z;
        }
        // ---- scale + causal mask ----
        const bool needmask = (kv0 + 31 > q0);
        #pragma unroll
        for (int nt = 0; nt < 2; ++nt)
            #pragma unroll
            for (int r = 0; r < 4; ++r) {
                float v = s[nt][r] * 0.125f;   // 1/sqrt(64)
                if (needmask && (kv0 + nt * 16 + c16 > q0 + g * 4 + r)) v = -1e30f;
                s[nt][r] = v;
            }
        // ---- row max (reduce across the 16 lanes holding one row) ----
        float mx[4];
        #pragma unroll
        for (int r = 0; r < 4; ++r) mx[r] = fmaxf(s[0][r], s[1][r]);
        #pragma unroll
        for (int d = 1; d <= 8; d <<= 1)
            #pragma unroll
            for (int r = 0; r < 4; ++r)
                mx[r] = fmaxf(mx[r], __shfl_xor(mx[r], d));
        // ---- online softmax update ----
        float fr[4], ps[4];
        #pragma unroll
        for (int r = 0; r < 4; ++r) {
            float mn = fmaxf(m_r[r], mx[r]);
            fr[r] = exp2f((m_r[r] - mn) * LOG2E);
            m_r[r] = mn;
            ps[r] = 0.f;
        }
        unsigned short pb[2][4];
        #pragma unroll
        for (int nt = 0; nt < 2; ++nt)
            #pragma unroll
            for (int r = 0; r < 4; ++r) {
                float p = exp2f((s[nt][r] - m_r[r]) * LOG2E);
                ps[r] += p;
                pb[nt][r] = f2bf(p);
            }
        #pragma unroll
        for (int d = 1; d <= 8; d <<= 1)
            #pragma unroll
            for (int r = 0; r < 4; ++r)
                ps[r] += __shfl_xor(ps[r], d);
        #pragma unroll
        for (int r = 0; r < 4; ++r) l_r[r] = l_r[r] * fr[r] + ps[r];
        #pragma unroll
        for (int vt = 0; vt < 4; ++vt)
            #pragma unroll
            for (int r = 0; r < 4; ++r)
                acc[vt][r] *= fr[r];
        // ---- P (D-layout) -> LDS -> A-frag layout ----
        #pragma unroll
        for (int nt = 0; nt < 2; ++nt)
            #pragma unroll
            for (int r = 0; r < 4; ++r)
                Plds[g * 4 + r][nt * 16 + c16] = pb[nt][r];
        __syncthreads();   // single wave: just drains lgkm before the re-read
        short8 pf = *(const short8*)&Plds[c16][g * 8];
        // ---- PV: O += P @ V  (Vt rows are contiguous in s) ----
        #pragma unroll
        for (int vt = 0; vt < 4; ++vt) {
            short8 vf = *(const short8*)(Vbase + (long)(vt * 16 + c16) * 2048 + kv0 + g * 8);
            acc[vt] = MFMA16(pf, vf, acc[vt]);
        }
    }

    // ---- epilogue: divide by l, store fp32 ----
    float inv[4];
    #pragma unroll
    for (int r = 0; r < 4; ++r) inv[r] = 1.0f / l_r[r];
    #pragma unroll
    for (int vt = 0; vt < 4; ++vt)
        #pragma unroll
        for (int r = 0; r < 4; ++r)
            out[((long)b * 2048 + q0 + g * 4 + r) * 64 + vt * 16 + c16] =
                acc[vt][r] * inv[r];
}

extern "C" void kernel_launch(void* const* d_in, const int* in_sizes, int n_in,
                              void* d_out, int out_size, void* d_ws, size_t ws_size,
                              hipStream_t stream)
{
    const float* x  = (const float*)d_in[0];
    const float* wq = (const float*)d_in[1];
    const float* wk = (const float*)d_in[2];
    const float* wv = (const float*)d_in[3];

    unsigned short* Qb = (unsigned short*)d_ws;
    unsigned short* Kb = Qb + (size_t)16384 * 64;
    unsigned short* Vt = Kb + (size_t)16384 * 64;
    float* out = (float*)d_out;

    qkv_proj<<<dim3(256), dim3(256), 0, stream>>>(x, wq, wk, wv, Qb, Kb, Vt);
    attn_fwd<<<dim3(1024), dim3(64), 0, stream>>>(Qb, Kb, Vt, out);
}

// Round 2
// 74.636 us; speedup vs baseline: 1.5879x; 1.5879x over previous
//
#include <hip/hip_runtime.h>
#include <hip/hip_bf16.h>

// B=8, S=2048, D_MODEL=1024, D_K=D_V=64, causal, fp32 in/out.
// ws: Qb bf16[16384][64] | Kb bf16[16384][64] | Vt bf16[8][64][2048]

typedef __attribute__((ext_vector_type(4))) float f32x4;
typedef __attribute__((ext_vector_type(2))) float f32x2;
typedef __attribute__((ext_vector_type(8))) short short8;
typedef __attribute__((ext_vector_type(4))) short short4v;

#define MFMA16(a, b, c) __builtin_amdgcn_mfma_f32_16x16x32_bf16((a), (b), (c), 0, 0, 0)

__device__ __forceinline__ unsigned short f2bf(float f) {
    unsigned int u = __float_as_uint(f);
    unsigned int r = (u + 0x7FFFu + ((u >> 16) & 1u)) >> 16;
    return (unsigned short)r;
}
__device__ __forceinline__ unsigned int pk2(float a, float b) {
    return (unsigned int)f2bf(a) | ((unsigned int)f2bf(b) << 16);
}
__device__ __forceinline__ f32x4 zero4() {
    f32x4 z = {0.f, 0.f, 0.f, 0.f};
    return z;
}

// ---------------------------------------------------------------------------
// Kernel 1: QKV projection, BM=64 x BN=192, K-step 32, double-buffered LDS.
// 1024 threads (16 waves as 4x4): wave tile 16 rows x 48 cols, acc[3].
// ---------------------------------------------------------------------------
__global__ __launch_bounds__(1024) void qkv_proj(
    const float* __restrict__ x,
    const float* __restrict__ wq,
    const float* __restrict__ wk,
    const float* __restrict__ wv,
    unsigned short* __restrict__ Qb,
    unsigned short* __restrict__ Kb,
    unsigned short* __restrict__ Vt)
{
    // stride 40 u16 = 80 B: 16B-aligned for b128, 2-way bank alias only (free)
    __shared__ __align__(16) unsigned short Alds[2][64][40];
    __shared__ __align__(16) unsigned short Blds[2][192][40];

    const int tid  = threadIdx.x;
    const int lane = tid & 63;
    const int wid  = tid >> 6;          // 0..15
    const int c16  = lane & 15;
    const int g    = lane >> 4;
    const int wm   = wid >> 2;          // 0..3  (16-row group)
    const int wn   = wid & 3;           // 0..3  (48-col group)
    const long m0  = (long)blockIdx.x * 64;

    // staging map: ar = row 0..63, ac = float2-column 0..15 (32 floats per row chunk)
    const int ar = tid >> 4;
    const int ac = tid & 15;

    f32x2 ra, rb0, rb1, rb2;

    f32x4 acc[3];
    acc[0] = zero4(); acc[1] = zero4(); acc[2] = zero4();

    // prologue: chunk 0
    ra  = *(const f32x2*)(x  + (m0 + ar) * 1024 + ac * 2);
    rb0 = *(const f32x2*)(wq + (long)ar * 1024 + ac * 2);
    rb1 = *(const f32x2*)(wk + (long)ar * 1024 + ac * 2);
    rb2 = *(const f32x2*)(wv + (long)ar * 1024 + ac * 2);
    *(unsigned int*)&Alds[0][ar][ac * 2]       = pk2(ra[0], ra[1]);
    *(unsigned int*)&Blds[0][ar][ac * 2]       = pk2(rb0[0], rb0[1]);
    *(unsigned int*)&Blds[0][64 + ar][ac * 2]  = pk2(rb1[0], rb1[1]);
    *(unsigned int*)&Blds[0][128 + ar][ac * 2] = pk2(rb2[0], rb2[1]);
    __syncthreads();

    for (int it = 0; it < 32; ++it) {
        const int cur = it & 1;
        if (it < 31) {
            const int k0 = (it + 1) * 32;
            ra  = *(const f32x2*)(x  + (m0 + ar) * 1024 + k0 + ac * 2);
            rb0 = *(const f32x2*)(wq + (long)ar * 1024 + k0 + ac * 2);
            rb1 = *(const f32x2*)(wk + (long)ar * 1024 + k0 + ac * 2);
            rb2 = *(const f32x2*)(wv + (long)ar * 1024 + k0 + ac * 2);
        }
        short8 af  = *(const short8*)&Alds[cur][wm * 16 + c16][g * 8];
        short8 bf0 = *(const short8*)&Blds[cur][wn * 48 + c16][g * 8];
        short8 bf1 = *(const short8*)&Blds[cur][wn * 48 + 16 + c16][g * 8];
        short8 bf2 = *(const short8*)&Blds[cur][wn * 48 + 32 + c16][g * 8];
        acc[0] = MFMA16(af, bf0, acc[0]);
        acc[1] = MFMA16(af, bf1, acc[1]);
        acc[2] = MFMA16(af, bf2, acc[2]);
        if (it < 31) {
            const int nxt = cur ^ 1;
            *(unsigned int*)&Alds[nxt][ar][ac * 2]       = pk2(ra[0], ra[1]);
            *(unsigned int*)&Blds[nxt][ar][ac * 2]       = pk2(rb0[0], rb0[1]);
            *(unsigned int*)&Blds[nxt][64 + ar][ac * 2]  = pk2(rb1[0], rb1[1]);
            *(unsigned int*)&Blds[nxt][128 + ar][ac * 2] = pk2(rb2[0], rb2[1]);
        }
        __syncthreads();
    }

    // epilogue: D layout col=lane&15, row=g*4+r
    const long mrow = m0 + wm * 16 + g * 4;
    #pragma unroll
    for (int nt = 0; nt < 3; ++nt) {
        const int n = wn * 48 + nt * 16 + c16;
        if (n < 64) {
            #pragma unroll
            for (int r = 0; r < 4; ++r)
                Qb[(mrow + r) * 64 + n] = f2bf(acc[nt][r]);
        } else if (n < 128) {
            #pragma unroll
            for (int r = 0; r < 4; ++r)
                Kb[(mrow + r) * 64 + (n - 64)] = f2bf(acc[nt][r]);
        } else {
            const long bb = mrow >> 11;
            const long ss = mrow & 2047;
            short4v pv = { (short)f2bf(acc[nt][0]), (short)f2bf(acc[nt][1]),
                           (short)f2bf(acc[nt][2]), (short)f2bf(acc[nt][3]) };
            *(short4v*)&Vt[((bb * 64) + (n - 128)) * 2048 + ss] = pv;
        }
    }
}

// ---------------------------------------------------------------------------
// Kernel 2: causal flash attention, 4-way KV-split per Q-tile.
// Block = 256 thr (4 waves), one 16-row Q tile; wave w handles a contiguous
// quarter of the kv 32-blocks with its own online softmax; LDS merge at end.
// ---------------------------------------------------------------------------
__global__ __launch_bounds__(256) void attn_fwd(
    const unsigned short* __restrict__ Qb,
    const unsigned short* __restrict__ Kb,
    const unsigned short* __restrict__ Vt,
    float* __restrict__ out)
{
    __shared__ __align__(16) char smem[16896];
    // during kv loop: per-wave P tile [16][72] u16 at smem + wid*2304
    // after loop:     Obuf float[4][16][64] at 0, mlb float[4][32] at 16384

    const int tid  = threadIdx.x;
    const int lane = tid & 63;
    const int wid  = tid >> 6;
    const int c16  = lane & 15;
    const int g    = lane >> 4;
    const int bidx = blockIdx.x;
    const int b    = bidx & 7;              // batch == XCD id (L2 locality)
    const int qt   = 127 - (bidx >> 3);     // longest tiles launch first
    const int q0   = qt * 16;

    unsigned short (*P)[72] = (unsigned short (*)[72])(smem + wid * 2304);
    float* Obuf = (float*)smem;
    float* mlb  = (float*)(smem + 16384);

    const unsigned short* qrow = Qb + ((long)b * 2048 + q0 + c16) * 64;
    const short8 qf0 = *(const short8*)(qrow + g * 8);
    const short8 qf1 = *(const short8*)(qrow + 32 + g * 8);
    const unsigned short* Kbase = Kb + (long)b * 2048 * 64;
    const unsigned short* Vbase = Vt + (long)b * 64 * 2048;

    f32x4 acc[4];
    #pragma unroll
    for (int vt = 0; vt < 4; ++vt) acc[vt] = zero4();
    float m_r[4], l_r[4];
    #pragma unroll
    for (int r = 0; r < 4; ++r) { m_r[r] = -1e30f; l_r[r] = 0.f; }

    const float LOG2E = 1.44269504088896f;
    const int n_kv = q0 + 16;
    const int nb   = (n_kv + 31) >> 5;        // kv 32-blocks
    const int cl   = (nb + 3) >> 2;           // blocks per wave
    const int blo  = min(wid * cl, nb);
    const int bhi  = min(blo + cl, nb);

    for (int blk = blo; blk < bhi; ++blk) {
        const int kv0 = blk * 32;
        // ---- V loads issued early (independent of S chain) ----
        short8 vf[4];
        #pragma unroll
        for (int vt = 0; vt < 4; ++vt)
            vf[vt] = *(const short8*)(Vbase + (long)(vt * 16 + c16) * 2048 + kv0 + g * 8);
        // ---- S = Q K^T (16 x 32) ----
        f32x4 s[2];
        #pragma unroll
        for (int nt = 0; nt < 2; ++nt) {
            const unsigned short* krow = Kbase + (long)(kv0 + nt * 16 + c16) * 64;
            short8 kf0 = *(const short8*)(krow + g * 8);
            short8 kf1 = *(const short8*)(krow + 32 + g * 8);
            f32x4 z = zero4();
            z = MFMA16(qf0, kf0, z);
            z = MFMA16(qf1, kf1, z);
            s[nt] = z;
        }
        // ---- scale + causal mask ----
        const bool needmask = (kv0 + 31 > q0);
        #pragma unroll
        for (int nt = 0; nt < 2; ++nt)
            #pragma unroll
            for (int r = 0; r < 4; ++r) {
                float v = s[nt][r] * 0.125f;
                if (needmask && (kv0 + nt * 16 + c16 > q0 + g * 4 + r)) v = -1e30f;
                s[nt][r] = v;
            }
        // ---- row max across 16 lanes ----
        float mx[4];
        #pragma unroll
        for (int r = 0; r < 4; ++r) mx[r] = fmaxf(s[0][r], s[1][r]);
        #pragma unroll
        for (int d = 1; d <= 8; d <<= 1)
            #pragma unroll
            for (int r = 0; r < 4; ++r)
                mx[r] = fmaxf(mx[r], __shfl_xor(mx[r], d));
        // ---- online softmax ----
        float fr[4], ps[4];
        #pragma unroll
        for (int r = 0; r < 4; ++r) {
            float mn = fmaxf(m_r[r], mx[r]);
            fr[r] = exp2f((m_r[r] - mn) * LOG2E);
            m_r[r] = mn;
            ps[r] = 0.f;
        }
        unsigned short pb[2][4];
        #pragma unroll
        for (int nt = 0; nt < 2; ++nt)
            #pragma unroll
            for (int r = 0; r < 4; ++r) {
                float p = exp2f((s[nt][r] - m_r[r]) * LOG2E);
                ps[r] += p;
                pb[nt][r] = f2bf(p);
            }
        #pragma unroll
        for (int d = 1; d <= 8; d <<= 1)
            #pragma unroll
            for (int r = 0; r < 4; ++r)
                ps[r] += __shfl_xor(ps[r], d);
        #pragma unroll
        for (int r = 0; r < 4; ++r) l_r[r] = l_r[r] * fr[r] + ps[r];
        #pragma unroll
        for (int vt = 0; vt < 4; ++vt)
            #pragma unroll
            for (int r = 0; r < 4; ++r)
                acc[vt][r] *= fr[r];
        // ---- P (D layout) -> per-wave LDS -> A-frag ----
        #pragma unroll
        for (int nt = 0; nt < 2; ++nt)
            #pragma unroll
            for (int r = 0; r < 4; ++r)
                P[g * 4 + r][nt * 16 + c16] = pb[nt][r];
        asm volatile("s_waitcnt lgkmcnt(0)" ::: "memory");
        short8 pf = *(const short8*)&P[c16][g * 8];
        // ---- PV ----
        #pragma unroll
        for (int vt = 0; vt < 4; ++vt)
            acc[vt] = MFMA16(pf, vf[vt], acc[vt]);
    }

    // ---- write per-wave partials ----
    __syncthreads();   // all waves done with P region before overlay
    if (c16 == 0) {
        #pragma unroll
        for (int r = 0; r < 4; ++r) {
            mlb[wid * 32 + g * 4 + r]      = m_r[r];
            mlb[wid * 32 + 16 + g * 4 + r] = l_r[r];
        }
    }
    #pragma unroll
    for (int vt = 0; vt < 4; ++vt)
        #pragma unroll
        for (int r = 0; r < 4; ++r)
            Obuf[(wid * 16 + g * 4 + r) * 64 + vt * 16 + c16] = acc[vt][r];
    __syncthreads();

    // ---- merge 4 partials; each thread owns 1 row x 4 cols ----
    const int row = tid >> 4;
    const int c0  = (tid & 15) * 4;
    float mm = -1e30f;
    #pragma unroll
    for (int w = 0; w < 4; ++w) mm = fmaxf(mm, mlb[w * 32 + row]);
    float sw[4], l = 0.f;
    #pragma unroll
    for (int w = 0; w < 4; ++w) {
        sw[w] = exp2f((mlb[w * 32 + row] - mm) * LOG2E);
        l += mlb[w * 32 + 16 + row] * sw[w];
    }
    const float inv = 1.0f / l;
    f32x4 o = zero4();
    #pragma unroll
    for (int w = 0; w < 4; ++w) {
        const float* Orow = Obuf + (w * 16 + row) * 64 + c0;
        #pragma unroll
        for (int j = 0; j < 4; ++j) o[j] += Orow[j] * sw[w];
    }
    #pragma unroll
    for (int j = 0; j < 4; ++j) o[j] *= inv;
    *(f32x4*)(out + ((long)b * 2048 + q0 + row) * 64 + c0) = o;
}

extern "C" void kernel_launch(void* const* d_in, const int* in_sizes, int n_in,
                              void* d_out, int out_size, void* d_ws, size_t ws_size,
                              hipStream_t stream)
{
    const float* x  = (const float*)d_in[0];
    const float* wq = (const float*)d_in[1];
    const float* wk = (const float*)d_in[2];
    const float* wv = (const float*)d_in[3];

    unsigned short* Qb = (unsigned short*)d_ws;
    unsigned short* Kb = Qb + (size_t)16384 * 64;
    unsigned short* Vt = Kb + (size_t)16384 * 64;
    float* out = (float*)d_out;

    qkv_proj<<<dim3(256), dim3(1024), 0, stream>>>(x, wq, wk, wv, Qb, Kb, Vt);
    attn_fwd<<<dim3(1024), dim3(256), 0, stream>>>(Qb, Kb, Vt, out);
}